// Round 2
// baseline (448.705 us; speedup 1.0000x reference)
//
#include <hip/hip_runtime.h>
#include <hip/hip_bf16.h>

#define NEG_SLOPE 0.2f
#define LN_EPS 1e-5f
#define D 64  // Din == Dout == 64

typedef unsigned long long u64;

// ---------------------------------------------------------------------------
// Kernel 1: hW = h @ W^T   (N x 64), plus s1[i] = hW[i].a1, s2[i] = hW[i].a2
// One wave per node: lane j owns output column j.
// ---------------------------------------------------------------------------
__global__ void k_hw_scores(const float* __restrict__ h,
                            const float* __restrict__ W,
                            const float* __restrict__ a,
                            float* __restrict__ hW,
                            float* __restrict__ s1,
                            float* __restrict__ s2,
                            int N) {
    __shared__ float Wt[D * D];   // Wt[k][j] = W[j][k]
    __shared__ float a_sh[2 * D];

    for (int idx = threadIdx.x; idx < D * D; idx += blockDim.x) {
        int j = idx >> 6, k = idx & 63;
        Wt[k * D + j] = W[j * D + k];
    }
    if (threadIdx.x < 2 * D) a_sh[threadIdx.x] = a[threadIdx.x];
    __syncthreads();

    const int lane = threadIdx.x & 63;
    const int wid  = threadIdx.x >> 6;
    const int wavesPerBlock = blockDim.x >> 6;
    const int nWaves = gridDim.x * wavesPerBlock;

    for (int i = blockIdx.x * wavesPerBlock + wid; i < N; i += nWaves) {
        float hv = h[(size_t)i * D + lane];
        float acc = 0.f;
        #pragma unroll
        for (int k = 0; k < D; ++k) {
            float hk = __shfl(hv, k, 64);
            acc = fmaf(hk, Wt[k * D + lane], acc);
        }
        hW[(size_t)i * D + lane] = acc;

        float p1 = acc * a_sh[lane];
        float p2 = acc * a_sh[D + lane];
        #pragma unroll
        for (int off = 32; off > 0; off >>= 1) {
            p1 += __shfl_xor(p1, off, 64);
            p2 += __shfl_xor(p2, off, 64);
        }
        if (lane == 0) { s1[i] = p1; s2[i] = p2; }
    }
}

// monotonic float<->uint mapping for atomicMax on floats
__device__ __forceinline__ unsigned f2u_mono(float x) {
    unsigned u = __float_as_uint(x);
    return (u & 0x80000000u) ? ~u : (u | 0x80000000u);
}
__device__ __forceinline__ float u2f_mono(unsigned u) {
    unsigned b = (u & 0x80000000u) ? (u ^ 0x80000000u) : ~u;
    return __uint_as_float(b);
}

// ---------------------------------------------------------------------------
// Kernel 2: per-edge e = leaky_relu(s1[src]+s2[dst]); segment max over src;
// dst histogram for CSR binning.
// ---------------------------------------------------------------------------
__global__ void k_edge_max_hist(const int* __restrict__ src,
                                const int* __restrict__ dst,
                                const float* __restrict__ s1,
                                const float* __restrict__ s2,
                                float* __restrict__ e_out,
                                unsigned* __restrict__ m_u,
                                int* __restrict__ count,
                                int E) {
    int idx = blockIdx.x * blockDim.x + threadIdx.x;
    if (idx >= E) return;
    int s = src[idx], d = dst[idx];
    float x = s1[s] + s2[d];
    float e = x > 0.f ? x : NEG_SLOPE * x;
    e_out[idx] = e;
    atomicMax(&m_u[s], f2u_mono(e));
    atomicAdd(&count[d], 1);
}

// ---------------------------------------------------------------------------
// Kernel 3: single-block chunked exclusive scan of count[0..N) -> rowptr[0..N]
// Also writes cursor[i] = rowptr[i] (binning cursors).
// 1024 threads x 8 elements per chunk.
// ---------------------------------------------------------------------------
__global__ void k_scan(const int* __restrict__ count,
                       int* __restrict__ rowptr,
                       int* __restrict__ cursor,
                       int N) {
    const int T = 1024, K = 8;
    __shared__ int buf[T];
    int tid = threadIdx.x;
    int carry = 0;
    for (int base = 0; base < N; base += T * K) {
        int v[K];
        int sum = 0;
        int idx0 = base + tid * K;
        #pragma unroll
        for (int k = 0; k < K; ++k) {
            int i = idx0 + k;
            int c = (i < N) ? count[i] : 0;
            v[k] = sum;          // exclusive prefix within thread
            sum += c;
        }
        buf[tid] = sum;
        __syncthreads();
        for (int off = 1; off < T; off <<= 1) {
            int t = (tid >= off) ? buf[tid - off] : 0;
            __syncthreads();
            buf[tid] += t;
            __syncthreads();
        }
        int texcl = buf[tid] - sum;      // exclusive prefix of thread totals
        int chunk_total = buf[T - 1];
        #pragma unroll
        for (int k = 0; k < K; ++k) {
            int i = idx0 + k;
            if (i < N) {
                int val = carry + texcl + v[k];
                rowptr[i] = val;
                cursor[i] = val;
            }
        }
        carry += chunk_total;
        __syncthreads();
    }
    if (tid == 0) rowptr[N] = carry;     // == E
}

// ---------------------------------------------------------------------------
// Kernel 4: ex = exp(e - m[src]); denom = segment_sum(ex) over src;
// bin edge into dst bucket as packed {src, ex} (8B).
// ---------------------------------------------------------------------------
__global__ void k_exp_bin(const int* __restrict__ src,
                          const int* __restrict__ dst,
                          const float* __restrict__ e_in,
                          const unsigned* __restrict__ m_u,
                          float* __restrict__ denom,
                          int* __restrict__ cursor,
                          u64* __restrict__ sorted,
                          int E) {
    int idx = blockIdx.x * blockDim.x + threadIdx.x;
    if (idx >= E) return;
    int s = src[idx], d = dst[idx];
    float m = u2f_mono(m_u[s]);
    float ex = expf(e_in[idx] - m);
    atomicAdd(&denom[s], ex);
    int slot = atomicAdd(&cursor[d], 1);
    sorted[slot] = ((u64)__float_as_uint(ex) << 32) | (unsigned)s;
}

// ---------------------------------------------------------------------------
// Kernel 5: fused aggregate + residual + LayerNorm. One wave per dst node.
//   acc[lane] = sum over in-edges of (ex/denom[src]) * hW[src][lane]
//   out[node] = LN(hW[node] + acc)
// ---------------------------------------------------------------------------
__global__ void k_aggregate_ln(const int* __restrict__ rowptr,
                               const u64* __restrict__ sorted,
                               const float* __restrict__ denom,
                               const float* __restrict__ hW,
                               const float* __restrict__ gamma,
                               const float* __restrict__ beta,
                               float* __restrict__ out,
                               int N) {
    int gtid = blockIdx.x * blockDim.x + threadIdx.x;
    int node = gtid >> 6;
    if (node >= N) return;
    int lane = gtid & 63;

    int beg = rowptr[node], end = rowptr[node + 1];
    float acc = 0.f;

    for (int k0 = beg; k0 < end; k0 += 64) {
        // wave-parallel prefetch of up to 64 edge records
        int kk = k0 + lane;
        int   s_l = 0;
        float att_l = 0.f;
        if (kk < end) {
            u64 p = sorted[kk];
            s_l = (int)(unsigned)(p & 0xffffffffull);
            float ex_l = __uint_as_float((unsigned)(p >> 32));
            att_l = ex_l / denom[s_l];
        }
        int nk = min(64, end - k0);      // wave-uniform
        for (int j = 0; j < nk; ++j) {
            int s = __shfl(s_l, j, 64);
            float att = __shfl(att_l, j, 64);
            acc = fmaf(att, hW[(size_t)s * D + lane], acc);
        }
    }

    float x = hW[(size_t)node * D + lane] + acc;

    float sm = x;
    #pragma unroll
    for (int off = 32; off > 0; off >>= 1) sm += __shfl_xor(sm, off, 64);
    float mu = sm * (1.f / D);

    float dx = x - mu;
    float v = dx * dx;
    #pragma unroll
    for (int off = 32; off > 0; off >>= 1) v += __shfl_xor(v, off, 64);
    float var = v * (1.f / D);

    out[(size_t)node * D + lane] = dx * rsqrtf(var + LN_EPS) * gamma[lane] + beta[lane];
}

// ---------------------------------------------------------------------------
static inline size_t align256(size_t x) { return (x + 255) & ~size_t(255); }

extern "C" void kernel_launch(void* const* d_in, const int* in_sizes, int n_in,
                              void* d_out, int out_size, void* d_ws, size_t ws_size,
                              hipStream_t stream) {
    const float* h    = (const float*)d_in[0];
    const int*   ei   = (const int*)d_in[1];
    const float* W    = (const float*)d_in[2];
    const float* a    = (const float*)d_in[3];
    const float* lng  = (const float*)d_in[4];
    const float* lnb  = (const float*)d_in[5];
    float* out = (float*)d_out;

    const int N = in_sizes[0] / D;
    const int E = in_sizes[1] / 2;
    const int* src = ei;        // edge_index[0]
    const int* dst = ei + E;    // edge_index[1]

    // workspace layout
    char* ws = (char*)d_ws;
    size_t off = 0;
    float* hW     = (float*)(ws + off); off += align256(sizeof(float) * (size_t)N * D);
    float* e_buf  = (float*)(ws + off); off += align256(sizeof(float) * (size_t)E);
    float* s1     = (float*)(ws + off); off += align256(sizeof(float) * (size_t)N);
    float* s2     = (float*)(ws + off); off += align256(sizeof(float) * (size_t)N);
    u64*   sorted = (u64*)  (ws + off); off += align256(sizeof(u64)   * (size_t)E);
    int*   rowptr = (int*)  (ws + off); off += align256(sizeof(int)   * (size_t)(N + 1));
    int*   cursor = (int*)  (ws + off); off += align256(sizeof(int)   * (size_t)N);
    // zero-initialized tail: m_u, denom, count (contiguous -> one memset)
    size_t zero_off = off;
    unsigned* m_u   = (unsigned*)(ws + off); off += align256(sizeof(unsigned) * (size_t)N);
    float*    denom = (float*)   (ws + off); off += align256(sizeof(float)    * (size_t)N);
    int*      count = (int*)     (ws + off); off += align256(sizeof(int)      * (size_t)N);
    size_t zero_bytes = off - zero_off;

    hipMemsetAsync(ws + zero_off, 0, zero_bytes, stream);

    // K1: hW + attention scores
    k_hw_scores<<<dim3(1024), dim3(256), 0, stream>>>(h, W, a, hW, s1, s2, N);

    // K2: e + segment max (src) + dst histogram
    k_edge_max_hist<<<dim3((E + 255) / 256), dim3(256), 0, stream>>>(
        src, dst, s1, s2, e_buf, m_u, count, E);

    // K3: exclusive scan -> rowptr, cursor
    k_scan<<<dim3(1), dim3(1024), 0, stream>>>(count, rowptr, cursor, N);

    // K4: exp + segment sum (src) + bin into dst-CSR
    k_exp_bin<<<dim3((E + 255) / 256), dim3(256), 0, stream>>>(
        src, dst, e_buf, m_u, denom, cursor, sorted, E);

    // K5: fused gather-aggregate + residual + LayerNorm (one wave per node)
    {
        size_t threads = (size_t)N * 64;
        k_aggregate_ln<<<dim3((unsigned)((threads + 255) / 256)), dim3(256), 0, stream>>>(
            rowptr, sorted, denom, hW, lng, lnb, out, N);
    }
}

// Round 4
// 274.963 us; speedup vs baseline: 1.6319x; 1.6319x over previous
//
#include <hip/hip_runtime.h>
#include <hip/hip_bf16.h>

#define NEG_SLOPE 0.2f
#define LN_EPS 1e-5f
#define D 64          // Din == Dout == 64
#define NBMAX 512     // max buckets (supports N <= 65536 at 128 nodes/bucket)
#define BCAP 3072     // records per bucket region (avg 2560 for N=50k,E=1M; ~10 sigma headroom)
#define OVFCAP 65536  // overflow list capacity (safety; normally 0 used)

typedef unsigned long long u64;

// ---------------------------------------------------------------------------
// Kernel 1: hW = h @ W^T   (N x 64), plus s1[i] = hW[i].a1, s2[i] = hW[i].a2
// One wave per node: lane j owns output column j.
// ---------------------------------------------------------------------------
__global__ void k_hw_scores(const float* __restrict__ h,
                            const float* __restrict__ W,
                            const float* __restrict__ a,
                            float* __restrict__ hW,
                            float* __restrict__ s1,
                            float* __restrict__ s2,
                            int N) {
    __shared__ float Wt[D * D];   // Wt[k][j] = W[j][k]
    __shared__ float a_sh[2 * D];

    for (int idx = threadIdx.x; idx < D * D; idx += blockDim.x) {
        int j = idx >> 6, k = idx & 63;
        Wt[k * D + j] = W[j * D + k];
    }
    if (threadIdx.x < 2 * D) a_sh[threadIdx.x] = a[threadIdx.x];
    __syncthreads();

    const int lane = threadIdx.x & 63;
    const int wid  = threadIdx.x >> 6;
    const int wavesPerBlock = blockDim.x >> 6;
    const int nWaves = gridDim.x * wavesPerBlock;

    for (int i = blockIdx.x * wavesPerBlock + wid; i < N; i += nWaves) {
        float hv = h[(size_t)i * D + lane];
        float acc = 0.f;
        #pragma unroll
        for (int k = 0; k < D; ++k) {
            float hk = __shfl(hv, k, 64);
            acc = fmaf(hk, Wt[k * D + lane], acc);
        }
        hW[(size_t)i * D + lane] = acc;

        float p1 = acc * a_sh[lane];
        float p2 = acc * a_sh[D + lane];
        #pragma unroll
        for (int off = 32; off > 0; off >>= 1) {
            p1 += __shfl_xor(p1, off, 64);
            p2 += __shfl_xor(p2, off, 64);
        }
        if (lane == 0) { s1[i] = p1; s2[i] = p2; }
    }
}

// ---------------------------------------------------------------------------
// Kernel 2: fused edge pass.
//  ex = exp(leaky_relu(s1[src]+s2[dst]))   [no max-subtract: softmax is
//  shift-invariant; clamp at 60 keeps exp finite for any input]
//  denom[src] += ex  (atomic)
//  record {ex, src, dst&127} appended to bucket region (dst>>7), with
//  per-block two-phase reservation so writes are block-contiguous runs.
// ---------------------------------------------------------------------------
__global__ void __launch_bounds__(256)
k_bin_denom(const int* __restrict__ src,
            const int* __restrict__ dst,
            const float* __restrict__ s1,
            const float* __restrict__ s2,
            float* __restrict__ denom,
            int* __restrict__ cnt_g,      // [NBMAX] bucket fill counters (zeroed)
            u64* __restrict__ recs,       // [nb * BCAP]
            u64* __restrict__ ovf_rec,    // [OVFCAP]
            int* __restrict__ ovf_dst,    // [OVFCAP]
            int* __restrict__ ovf_n,      // scalar (zeroed)
            int E, int nb) {
    const int TPB = 256, EPT = 16;        // 4096 edges per block
    __shared__ int lcnt[NBMAX], lbase[NBMAX], lfill[NBMAX];

    int chunk = blockIdx.x * (TPB * EPT);
    for (int i = threadIdx.x; i < NBMAX; i += TPB) { lcnt[i] = 0; lfill[i] = 0; }
    __syncthreads();

    int dv[EPT];
    #pragma unroll
    for (int j = 0; j < EPT; ++j) {
        int i = chunk + j * TPB + threadIdx.x;
        dv[j] = (i < E) ? dst[i] : -1;
        if (dv[j] >= 0) atomicAdd(&lcnt[dv[j] >> 7], 1);
    }
    __syncthreads();

    for (int b = threadIdx.x; b < nb; b += TPB) {
        int l = lcnt[b];
        if (l) lbase[b] = atomicAdd(&cnt_g[b], l);   // reserve contiguous run
    }
    __syncthreads();

    #pragma unroll
    for (int j = 0; j < EPT; ++j) {
        int i = chunk + j * TPB + threadIdx.x;
        if (i >= E) continue;
        int s = src[i], d = dv[j];
        float x = s1[s] + s2[d];
        float e = x > 0.f ? x : NEG_SLOPE * x;
        float ex = expf(fminf(e, 60.f));
        atomicAdd(&denom[s], ex);
        int b = d >> 7;
        u64 rec = ((u64)__float_as_uint(ex) << 32)
                | (unsigned)s | ((unsigned)(d & 127) << 20);   // src < 2^20
        int r = lbase[b] + atomicAdd(&lfill[b], 1);
        if (r < BCAP) {
            recs[(size_t)b * BCAP + r] = rec;
        } else {
            int o = atomicAdd(ovf_n, 1);
            if (o < OVFCAP) { ovf_rec[o] = rec; ovf_dst[o] = d; }
        }
    }
}

// ---------------------------------------------------------------------------
// Kernel 3: one block per bucket (128 dst nodes). Stage records in registers,
// group by local dst in LDS (hist -> scan -> scatter), aggregate
// acc = sum att*hW[src], then residual + LayerNorm, write out.
// ---------------------------------------------------------------------------
__global__ void __launch_bounds__(1024)
k_bucket_agg(const u64* __restrict__ recs,
             const int* __restrict__ cnt_g,
             const float* __restrict__ denom,
             const float* __restrict__ hW,
             const float* __restrict__ gamma,
             const float* __restrict__ beta,
             const u64* __restrict__ ovf_rec,
             const int* __restrict__ ovf_dst,
             const int* __restrict__ ovf_n_p,
             float* __restrict__ out,
             int N) {
    __shared__ u64 ro[BCAP];
    __shared__ int hh[128], oo[128], cc[128];

    const int b = blockIdx.x;
    const int tid = threadIdx.x;
    const int lane = tid & 63;
    const int wid  = tid >> 6;            // 16 waves
    const int node0 = b << 7;
    const int nn = min(128, N - node0);
    const int total = min(cnt_g[b], BCAP);

    float acc[8];
    #pragma unroll
    for (int k = 0; k < 8; ++k) acc[k] = 0.f;

    // stage up to 3072 records into registers (coalesced)
    u64 r0 = 0, r1 = 0, r2 = 0;
    const bool v0 = tid < total, v1 = tid + 1024 < total, v2 = tid + 2048 < total;
    const u64* base = recs + (size_t)b * BCAP;
    if (v0) r0 = base[tid];
    if (v1) r1 = base[tid + 1024];
    if (v2) r2 = base[tid + 2048];

    if (tid < 128) hh[tid] = 0;
    __syncthreads();
    if (v0) atomicAdd(&hh[((unsigned)r0 >> 20) & 127], 1);
    if (v1) atomicAdd(&hh[((unsigned)r1 >> 20) & 127], 1);
    if (v2) atomicAdd(&hh[((unsigned)r2 >> 20) & 127], 1);
    __syncthreads();

    // inclusive Hillis-Steele scan over 128 entries
    if (tid < 128) oo[tid] = hh[tid];
    __syncthreads();
    for (int off = 1; off < 128; off <<= 1) {
        int t = 0;
        if (tid < 128 && tid >= off) t = oo[tid - off];
        __syncthreads();
        if (tid < 128) oo[tid] += t;
        __syncthreads();
    }
    if (tid < 128) { int e_ = oo[tid] - hh[tid]; oo[tid] = e_; cc[tid] = e_; }
    __syncthreads();

    // scatter into dst-grouped LDS buffer
    if (v0) ro[atomicAdd(&cc[((unsigned)r0 >> 20) & 127], 1)] = r0;
    if (v1) ro[atomicAdd(&cc[((unsigned)r1 >> 20) & 127], 1)] = r1;
    if (v2) ro[atomicAdd(&cc[((unsigned)r2 >> 20) & 127], 1)] = r2;
    __syncthreads();

    // aggregate: wave wid owns local nodes wid, wid+16, ..., wid+112
    #pragma unroll
    for (int k = 0; k < 8; ++k) {
        int nl = wid + (k << 4);
        if (nl >= nn) break;
        int beg = oo[nl], end = cc[nl];
        for (int p = beg; p < end; p += 64) {
            int idx = p + lane;
            int sl = 0; float attl = 0.f;
            if (idx < end) {
                u64 rr = ro[idx];
                int s = (unsigned)rr & 0xFFFFF;
                float ex = __uint_as_float((unsigned)(rr >> 32));
                attl = ex / denom[s];
                sl = s;
            }
            int nk = min(64, end - p);
            for (int j = 0; j < nk; ++j) {
                int s = __shfl(sl, j, 64);
                float at = __shfl(attl, j, 64);
                acc[k] = fmaf(at, hW[(size_t)s * D + lane], acc[k]);
            }
        }
    }

    // overflow safety path (normally ovn == 0)
    int ovn = *ovf_n_p;
    if (ovn > OVFCAP) ovn = OVFCAP;
    for (int r = 0; r < ovn; ++r) {
        int d = ovf_dst[r];
        if ((d >> 7) != b) continue;
        int dl = d & 127;
        if ((dl & 15) == wid && dl < nn) {
            u64 rr = ovf_rec[r];
            int s = (unsigned)rr & 0xFFFFF;
            float ex = __uint_as_float((unsigned)(rr >> 32));
            float at = ex / denom[s];
            acc[dl >> 4] = fmaf(at, hW[(size_t)s * D + lane], acc[dl >> 4]);
        }
    }

    // residual + LayerNorm
    #pragma unroll
    for (int k = 0; k < 8; ++k) {
        int nl = wid + (k << 4);
        if (nl >= nn) break;
        int n = node0 + nl;
        float x = hW[(size_t)n * D + lane] + acc[k];

        float sm = x;
        #pragma unroll
        for (int off = 32; off > 0; off >>= 1) sm += __shfl_xor(sm, off, 64);
        float mu = sm * (1.f / D);

        float dx = x - mu;
        float v = dx * dx;
        #pragma unroll
        for (int off = 32; off > 0; off >>= 1) v += __shfl_xor(v, off, 64);
        float var = v * (1.f / D);

        out[(size_t)n * D + lane] = dx * rsqrtf(var + LN_EPS) * gamma[lane] + beta[lane];
    }
}

// ---------------------------------------------------------------------------
static inline size_t align256(size_t x) { return (x + 255) & ~size_t(255); }

extern "C" void kernel_launch(void* const* d_in, const int* in_sizes, int n_in,
                              void* d_out, int out_size, void* d_ws, size_t ws_size,
                              hipStream_t stream) {
    const float* h    = (const float*)d_in[0];
    const int*   ei   = (const int*)d_in[1];
    const float* W    = (const float*)d_in[2];
    const float* a    = (const float*)d_in[3];
    const float* lng  = (const float*)d_in[4];
    const float* lnb  = (const float*)d_in[5];
    float* out = (float*)d_out;

    const int N = in_sizes[0] / D;
    const int E = in_sizes[1] / 2;
    const int* src = ei;        // edge_index[0]
    const int* dst = ei + E;    // edge_index[1]
    const int nb = (N + 127) >> 7;   // buckets of 128 dst nodes (<= NBMAX)

    // workspace layout
    char* ws = (char*)d_ws;
    size_t off = 0;
    float* hW      = (float*)(ws + off); off += align256(sizeof(float) * (size_t)N * D);
    float* s1      = (float*)(ws + off); off += align256(sizeof(float) * (size_t)N);
    float* s2      = (float*)(ws + off); off += align256(sizeof(float) * (size_t)N);
    u64*   recs    = (u64*)  (ws + off); off += align256(sizeof(u64) * (size_t)nb * BCAP);
    u64*   ovf_rec = (u64*)  (ws + off); off += align256(sizeof(u64) * (size_t)OVFCAP);
    int*   ovf_dst = (int*)  (ws + off); off += align256(sizeof(int) * (size_t)OVFCAP);
    // zero-initialized tail: denom, cnt_g, ovf_n (contiguous -> one memset)
    size_t zero_off = off;
    float* denom   = (float*)(ws + off); off += align256(sizeof(float) * (size_t)N);
    int*   cnt_g   = (int*)  (ws + off); off += align256(sizeof(int) * (size_t)NBMAX);
    int*   ovf_n   = (int*)  (ws + off); off += align256(sizeof(int));
    size_t zero_bytes = off - zero_off;

    hipMemsetAsync(ws + zero_off, 0, zero_bytes, stream);

    // K1: hW + attention scores
    k_hw_scores<<<dim3(1024), dim3(256), 0, stream>>>(h, W, a, hW, s1, s2, N);

    // K2: fused exp + denom + bucket binning (4096 edges per block)
    k_bin_denom<<<dim3((E + 4095) / 4096), dim3(256), 0, stream>>>(
        src, dst, s1, s2, denom, cnt_g, recs, ovf_rec, ovf_dst, ovf_n, E, nb);

    // K3: fused bucket sort + aggregate + residual + LayerNorm
    k_bucket_agg<<<dim3(nb), dim3(1024), 0, stream>>>(
        recs, cnt_g, denom, hW, lng, lnb, ovf_rec, ovf_dst, ovf_n, out, N);
}

// Round 5
// 228.127 us; speedup vs baseline: 1.9669x; 1.2053x over previous
//
#include <hip/hip_runtime.h>
#include <hip/hip_bf16.h>

#define NEG_SLOPE 0.2f
#define LN_EPS 1e-5f
#define D 64          // Din == Dout == 64
#define BSH 6         // 64 dst-nodes per bucket
#define BNODES 64
#define NBMAX 1024    // supports N <= 65536
#define BCAP 1792     // records per bucket (avg 1280 for N=50k,E=1M; +14 sigma)
#define OVFCAP 65536  // overflow list capacity (safety; normally 0 used)

typedef unsigned long long u64;

// ---------------------------------------------------------------------------
// Kernel 1: hW = h @ W^T   (N x 64), plus s1[i] = hW[i].a1, s2[i] = hW[i].a2
// One wave per node: lane j owns output column j.
// ---------------------------------------------------------------------------
__global__ void k_hw_scores(const float* __restrict__ h,
                            const float* __restrict__ W,
                            const float* __restrict__ a,
                            float* __restrict__ hW,
                            float* __restrict__ s1,
                            float* __restrict__ s2,
                            int N) {
    __shared__ float Wt[D * D];   // Wt[k][j] = W[j][k]
    __shared__ float a_sh[2 * D];

    for (int idx = threadIdx.x; idx < D * D; idx += blockDim.x) {
        int j = idx >> 6, k = idx & 63;
        Wt[k * D + j] = W[j * D + k];
    }
    if (threadIdx.x < 2 * D) a_sh[threadIdx.x] = a[threadIdx.x];
    __syncthreads();

    const int lane = threadIdx.x & 63;
    const int wid  = threadIdx.x >> 6;
    const int wavesPerBlock = blockDim.x >> 6;
    const int nWaves = gridDim.x * wavesPerBlock;

    for (int i = blockIdx.x * wavesPerBlock + wid; i < N; i += nWaves) {
        float hv = h[(size_t)i * D + lane];
        float acc = 0.f;
        #pragma unroll
        for (int k = 0; k < D; ++k) {
            float hk = __shfl(hv, k, 64);
            acc = fmaf(hk, Wt[k * D + lane], acc);
        }
        hW[(size_t)i * D + lane] = acc;

        float p1 = acc * a_sh[lane];
        float p2 = acc * a_sh[D + lane];
        #pragma unroll
        for (int off = 32; off > 0; off >>= 1) {
            p1 += __shfl_xor(p1, off, 64);
            p2 += __shfl_xor(p2, off, 64);
        }
        if (lane == 0) { s1[i] = p1; s2[i] = p2; }
    }
}

// ---------------------------------------------------------------------------
// Kernel 2: fused edge pass.
//  ex = exp(leaky_relu(s1[src]+s2[dst]))   [no max-subtract: softmax is
//  shift-invariant; clamp at 60 keeps exp finite]
//  denom[src] += ex  (atomic)
//  record {ex, dstlocal, src} appended to bucket region (dst>>6) with
//  per-block two-phase reservation -> block-contiguous runs.
// ---------------------------------------------------------------------------
__global__ void __launch_bounds__(256)
k_bin_denom(const int* __restrict__ src,
            const int* __restrict__ dst,
            const float* __restrict__ s1,
            const float* __restrict__ s2,
            float* __restrict__ denom,
            int* __restrict__ cnt_g,      // [nb] bucket fill counters (zeroed)
            u64* __restrict__ recs,       // [nb * BCAP]
            u64* __restrict__ ovf_rec,    // [OVFCAP]
            int* __restrict__ ovf_dst,    // [OVFCAP]
            int* __restrict__ ovf_n,      // scalar (zeroed)
            int E, int nb) {
    const int TPB = 256, EPT = 16;        // 4096 edges per block
    __shared__ int lcnt[NBMAX], lbase[NBMAX], lfill[NBMAX];

    const int chunk = blockIdx.x * (TPB * EPT);
    for (int i = threadIdx.x; i < nb; i += TPB) { lcnt[i] = 0; lfill[i] = 0; }
    __syncthreads();

    int sv[EPT], dv[EPT];
    const int e0 = chunk + threadIdx.x * EPT;
    if (e0 + EPT <= E) {
        const int4* sp = (const int4*)(src + e0);
        const int4* dp = (const int4*)(dst + e0);
        #pragma unroll
        for (int q = 0; q < 4; ++q) {
            int4 s4 = sp[q], d4 = dp[q];
            sv[q*4+0] = s4.x; sv[q*4+1] = s4.y; sv[q*4+2] = s4.z; sv[q*4+3] = s4.w;
            dv[q*4+0] = d4.x; dv[q*4+1] = d4.y; dv[q*4+2] = d4.z; dv[q*4+3] = d4.w;
        }
    } else {
        #pragma unroll
        for (int j = 0; j < EPT; ++j) {
            int i = e0 + j;
            sv[j] = (i < E) ? src[i] : 0;
            dv[j] = (i < E) ? dst[i] : -1;
        }
    }

    #pragma unroll
    for (int j = 0; j < EPT; ++j)
        if (dv[j] >= 0) atomicAdd(&lcnt[dv[j] >> BSH], 1);
    __syncthreads();

    for (int b = threadIdx.x; b < nb; b += TPB) {
        int l = lcnt[b];
        if (l) lbase[b] = atomicAdd(&cnt_g[b], l);   // reserve contiguous run
    }
    __syncthreads();

    #pragma unroll
    for (int j = 0; j < EPT; ++j) {
        int d_ = dv[j];
        if (d_ < 0) continue;
        int s = sv[j];
        float x = s1[s] + s2[d_];
        float e = x > 0.f ? x : NEG_SLOPE * x;
        float ex = expf(fminf(e, 60.f));
        atomicAdd(&denom[s], ex);
        int b = d_ >> BSH;
        // pack: [ex:32][0:6][dstl:6][src:20]
        u64 rec = ((u64)__float_as_uint(ex) << 32)
                | (unsigned)s | ((unsigned)(d_ & (BNODES - 1)) << 20);
        int r = lbase[b] + atomicAdd(&lfill[b], 1);
        if (r < BCAP) {
            recs[(size_t)b * BCAP + r] = rec;
        } else {
            int o = atomicAdd(ovf_n, 1);
            if (o < OVFCAP) { ovf_rec[o] = rec; ovf_dst[o] = d_; }
        }
    }
}

// ---------------------------------------------------------------------------
// Kernel 3: one block (512 thr, 8 waves) per 64-node bucket.
// Stage records, fold att = ex/denom[src], group by local dst in LDS,
// then aggregate with 4-edges-per-wave float4 gathers, residual + LN.
// Lane layout in aggregation: g = lane>>4 (edge slot), li = lane&15 (col/4).
// ---------------------------------------------------------------------------
__global__ void __launch_bounds__(512)
k_bucket_agg(const u64* __restrict__ recs,
             const int* __restrict__ cnt_g,
             const float* __restrict__ denom,
             const float* __restrict__ hW,
             const float* __restrict__ gamma,
             const float* __restrict__ beta,
             const u64* __restrict__ ovf_rec,
             const int* __restrict__ ovf_dst,
             const int* __restrict__ ovf_n_p,
             float* __restrict__ out,
             int N) {
    __shared__ u64 ro[BCAP];
    __shared__ int hh[BNODES], oo[BNODES], cc[BNODES];

    const int b    = blockIdx.x;
    const int tid  = threadIdx.x;
    const int lane = tid & 63;
    const int wid  = tid >> 6;            // 8 waves
    const int g    = lane >> 4;           // edge-slot group 0..3
    const int li   = lane & 15;           // column quad 0..15
    const int node0 = b << BSH;
    const int nn    = min(BNODES, N - node0);
    const int total = min(cnt_g[b], BCAP);

    // ---- stage records (coalesced) + fold att ----
    u64 rr[4]; bool valid[4];
    const u64* base = recs + (size_t)b * BCAP;
    #pragma unroll
    for (int q = 0; q < 4; ++q) {
        int idx = tid + q * 512;
        valid[q] = idx < total;
        rr[q] = valid[q] ? base[idx] : 0;
    }
    if (tid < BNODES) hh[tid] = 0;
    __syncthreads();

    #pragma unroll
    for (int q = 0; q < 4; ++q) if (valid[q]) {
        int s = (unsigned)rr[q] & 0xFFFFF;
        float ex = __uint_as_float((unsigned)(rr[q] >> 32));
        float att = ex / denom[s];
        rr[q] = (rr[q] & 0xFFFFFFFFull) | ((u64)__float_as_uint(att) << 32);
        atomicAdd(&hh[((unsigned)rr[q] >> 20) & (BNODES - 1)], 1);
    }
    __syncthreads();

    // ---- exclusive scan over 64 counters ----
    if (tid < BNODES) oo[tid] = hh[tid];
    __syncthreads();
    for (int off = 1; off < BNODES; off <<= 1) {
        int t = 0;
        if (tid < BNODES && tid >= off) t = oo[tid - off];
        __syncthreads();
        if (tid < BNODES) oo[tid] += t;
        __syncthreads();
    }
    if (tid < BNODES) { int e_ = oo[tid] - hh[tid]; oo[tid] = e_; cc[tid] = e_; }
    __syncthreads();

    // ---- scatter into dst-grouped LDS buffer ----
    #pragma unroll
    for (int q = 0; q < 4; ++q) if (valid[q])
        ro[atomicAdd(&cc[((unsigned)rr[q] >> 20) & (BNODES - 1)], 1)] = rr[q];
    __syncthreads();

    int ovn = *ovf_n_p;
    if (ovn > OVFCAP) ovn = OVFCAP;

    // ---- aggregate + residual + LayerNorm; wave owns nodes [wid*8, wid*8+8) ----
    #pragma unroll
    for (int k = 0; k < 8; ++k) {
        int nl = (wid << 3) + k;
        if (nl >= nn) break;
        int beg = oo[nl], end = cc[nl];

        float ax = 0.f, ay = 0.f, az = 0.f, aw = 0.f;
        for (int p = beg; p < end; p += 4) {
            int idx = p + g;
            float att = 0.f; int s = 0;
            if (idx < end) {
                u64 r2 = ro[idx];
                s = (unsigned)r2 & 0xFFFFF;
                att = __uint_as_float((unsigned)(r2 >> 32));
            }
            const float4 v = *(const float4*)(hW + (size_t)s * D + li * 4);
            ax = fmaf(att, v.x, ax); ay = fmaf(att, v.y, ay);
            az = fmaf(att, v.z, az); aw = fmaf(att, v.w, aw);
        }

        // overflow safety path (normally ovn == 0); add on group 0 only
        for (int r = 0; r < ovn; ++r) {
            if (ovf_dst[r] != node0 + nl) continue;
            if (g == 0) {
                u64 r2 = ovf_rec[r];
                int s = (unsigned)r2 & 0xFFFFF;
                float ex = __uint_as_float((unsigned)(r2 >> 32));
                float att = ex / denom[s];
                const float4 v = *(const float4*)(hW + (size_t)s * D + li * 4);
                ax = fmaf(att, v.x, ax); ay = fmaf(att, v.y, ay);
                az = fmaf(att, v.z, az); aw = fmaf(att, v.w, aw);
            }
        }

        // reduce across the 4 edge-slot groups
        ax += __shfl_xor(ax, 16, 64); ax += __shfl_xor(ax, 32, 64);
        ay += __shfl_xor(ay, 16, 64); ay += __shfl_xor(ay, 32, 64);
        az += __shfl_xor(az, 16, 64); az += __shfl_xor(az, 32, 64);
        aw += __shfl_xor(aw, 16, 64); aw += __shfl_xor(aw, 32, 64);

        // residual
        const float4 hv = *(const float4*)(hW + (size_t)(node0 + nl) * D + li * 4);
        float x0 = hv.x + ax, x1 = hv.y + ay, x2 = hv.z + az, x3 = hv.w + aw;

        // LayerNorm over 64 cols (16-lane groups hold replicated data)
        float sm = x0 + x1 + x2 + x3;
        sm += __shfl_xor(sm, 1, 64); sm += __shfl_xor(sm, 2, 64);
        sm += __shfl_xor(sm, 4, 64); sm += __shfl_xor(sm, 8, 64);
        float mu = sm * (1.f / D);
        float d0 = x0 - mu, d1 = x1 - mu, d2 = x2 - mu, d3 = x3 - mu;
        float vv = d0 * d0 + d1 * d1 + d2 * d2 + d3 * d3;
        vv += __shfl_xor(vv, 1, 64); vv += __shfl_xor(vv, 2, 64);
        vv += __shfl_xor(vv, 4, 64); vv += __shfl_xor(vv, 8, 64);
        float inv = rsqrtf(vv * (1.f / D) + LN_EPS);

        if (g == 0) {
            const float4 gm = *(const float4*)(gamma + li * 4);
            const float4 bt = *(const float4*)(beta + li * 4);
            float4 o;
            o.x = d0 * inv * gm.x + bt.x;
            o.y = d1 * inv * gm.y + bt.y;
            o.z = d2 * inv * gm.z + bt.z;
            o.w = d3 * inv * gm.w + bt.w;
            *(float4*)(out + (size_t)(node0 + nl) * D + li * 4) = o;
        }
    }
}

// ---------------------------------------------------------------------------
static inline size_t align256(size_t x) { return (x + 255) & ~size_t(255); }

extern "C" void kernel_launch(void* const* d_in, const int* in_sizes, int n_in,
                              void* d_out, int out_size, void* d_ws, size_t ws_size,
                              hipStream_t stream) {
    const float* h    = (const float*)d_in[0];
    const int*   ei   = (const int*)d_in[1];
    const float* W    = (const float*)d_in[2];
    const float* a    = (const float*)d_in[3];
    const float* lng  = (const float*)d_in[4];
    const float* lnb  = (const float*)d_in[5];
    float* out = (float*)d_out;

    const int N = in_sizes[0] / D;
    const int E = in_sizes[1] / 2;
    const int* src = ei;        // edge_index[0]
    const int* dst = ei + E;    // edge_index[1]
    const int nb = (N + BNODES - 1) >> BSH;   // 64-node buckets (<= NBMAX)

    // workspace layout
    char* ws = (char*)d_ws;
    size_t off = 0;
    float* hW      = (float*)(ws + off); off += align256(sizeof(float) * (size_t)N * D);
    float* s1      = (float*)(ws + off); off += align256(sizeof(float) * (size_t)N);
    float* s2      = (float*)(ws + off); off += align256(sizeof(float) * (size_t)N);
    u64*   recs    = (u64*)  (ws + off); off += align256(sizeof(u64) * (size_t)nb * BCAP);
    u64*   ovf_rec = (u64*)  (ws + off); off += align256(sizeof(u64) * (size_t)OVFCAP);
    int*   ovf_dst = (int*)  (ws + off); off += align256(sizeof(int) * (size_t)OVFCAP);
    // zero-initialized tail: denom, cnt_g, ovf_n (contiguous -> one memset)
    size_t zero_off = off;
    float* denom   = (float*)(ws + off); off += align256(sizeof(float) * (size_t)N);
    int*   cnt_g   = (int*)  (ws + off); off += align256(sizeof(int) * (size_t)NBMAX);
    int*   ovf_n   = (int*)  (ws + off); off += align256(sizeof(int));
    size_t zero_bytes = off - zero_off;

    hipMemsetAsync(ws + zero_off, 0, zero_bytes, stream);

    // K1: hW + attention scores
    k_hw_scores<<<dim3(1024), dim3(256), 0, stream>>>(h, W, a, hW, s1, s2, N);

    // K2: fused exp + denom + bucket binning (4096 edges per block)
    k_bin_denom<<<dim3((E + 4095) / 4096), dim3(256), 0, stream>>>(
        src, dst, s1, s2, denom, cnt_g, recs, ovf_rec, ovf_dst, ovf_n, E, nb);

    // K3: fused bucket sort + aggregate + residual + LayerNorm
    k_bucket_agg<<<dim3(nb), dim3(512), 0, stream>>>(
        recs, cnt_g, denom, hW, lng, lnb, ovf_rec, ovf_dst, ovf_n, out, N);
}